// Round 2
// baseline (1588.940 us; speedup 1.0000x reference)
//
#include <hip/hip_runtime.h>

#define E_EDGES 320000
#define N_NODES 10000

typedef __attribute__((ext_vector_type(8))) short bf16x8;
typedef __attribute__((ext_vector_type(4))) float f32x4;

__device__ __forceinline__ unsigned short f2bf(float x) {
  union { float f; unsigned u; } v; v.f = x;
  unsigned r = v.u + 0x7FFFu + ((v.u >> 16) & 1u);
  return (unsigned short)(r >> 16);
}
__device__ __forceinline__ float bf2f(unsigned short s) {
  union { unsigned u; float f; } v; v.u = ((unsigned)s) << 16;
  return v.f;
}

// ---------------- prep: W1 -> W1at/W1bt bf16 [n][k], W2 -> W2t bf16 [n][k] ----
__global__ __launch_bounds__(256) void prep_kernel(
    const float* __restrict__ W1, const float* __restrict__ W2,
    unsigned short* __restrict__ W1at, unsigned short* __restrict__ W1bt,
    unsigned short* __restrict__ W2t) {
  int tid = blockIdx.x * 256 + threadIdx.x;
  if (tid < 512 * 256) {
    int n = tid >> 8, k = tid & 255;          // W1at/W1bt: [512 n][256 k]
    W1at[tid] = f2bf(W1[k * 512 + n]);
    W1bt[tid] = f2bf(W1[(k + 256) * 512 + n]);
  } else {
    int t = tid - 512 * 256;
    if (t < 256 * 512) {
      int n = t >> 9, k = t & 511;            // W2t: [256 n][512 k]
      W2t[t] = f2bf(W2[k * 256 + n]);
    }
  }
}

// ---------------- U = x_in @ W1[0:256,:] + b1   -> bf16 [node][512] ----------
__global__ __launch_bounds__(256) void u_kernel(
    const float* __restrict__ x_in, const unsigned short* __restrict__ W1at,
    const float* __restrict__ b1, unsigned short* __restrict__ U) {
  __shared__ unsigned short x_lds[64 * 264];
  int tid = threadIdx.x;
  int m0g = blockIdx.x * 64;
  // stage 64x256 fp32 tile as bf16: 4096 float4 loads -> 16 iters of 256
  for (int it = 0; it < 16; ++it) {
    int i = it * 256 + tid;
    int r = i >> 6, c = i & 63;
    int node = m0g + r;
    float4 v = make_float4(0.f, 0.f, 0.f, 0.f);
    if (node < N_NODES) v = *(const float4*)(x_in + node * 256 + c * 4);
    unsigned short* d = x_lds + r * 264 + c * 4;
    d[0] = f2bf(v.x); d[1] = f2bf(v.y); d[2] = f2bf(v.z); d[3] = f2bf(v.w);
  }
  __syncthreads();
  int w = tid >> 6, l = tid & 63, quad = l >> 4, lid = l & 15;
  int cb = w * 128;
  f32x4 acc[4][8];
#pragma unroll
  for (int a = 0; a < 4; ++a)
#pragma unroll
    for (int b = 0; b < 8; ++b) acc[a][b] = (f32x4){0.f, 0.f, 0.f, 0.f};
#pragma unroll
  for (int kk = 0; kk < 8; ++kk) {
    bf16x8 af[4];
#pragma unroll
    for (int mf = 0; mf < 4; ++mf)
      af[mf] = *(const bf16x8*)(x_lds + (mf * 16 + lid) * 264 + kk * 32 + quad * 8);
#pragma unroll
    for (int nf = 0; nf < 8; ++nf) {
      bf16x8 bfr = *(const bf16x8*)(W1at + (cb + nf * 16 + lid) * 256 + kk * 32 + quad * 8);
#pragma unroll
      for (int mf = 0; mf < 4; ++mf)
        acc[mf][nf] = __builtin_amdgcn_mfma_f32_16x16x32_bf16(af[mf], bfr, acc[mf][nf], 0, 0, 0);
    }
  }
#pragma unroll
  for (int nf = 0; nf < 8; ++nf) {
    int col = cb + nf * 16 + lid;
    float b1v = b1[col];
#pragma unroll
    for (int mf = 0; mf < 4; ++mf)
#pragma unroll
      for (int reg = 0; reg < 4; ++reg) {
        int node = m0g + mf * 16 + quad * 4 + reg;
        if (node < N_NODES) U[node * 512 + col] = f2bf(acc[mf][nf][reg] + b1v);
      }
  }
}

// ---------------- fused edge MLP + scatter ----------------------------------
// 64 edges/WG; 4 waves column-split (64 rows x 64 cols per wave, 4x4 frags)
__global__ __launch_bounds__(256) void main_kernel(
    const int* __restrict__ EI, const float* __restrict__ edge_attr,
    const unsigned short* __restrict__ W1bt, const unsigned short* __restrict__ W2t,
    const unsigned short* __restrict__ U, const float* __restrict__ b2,
    float* __restrict__ out) {
  __shared__ unsigned short ea_lds[64 * 264];   // edge_attr bf16 [64][256+8]
  __shared__ unsigned short uh_lds[64 * 264];   // U chunk, then h chunk
  __shared__ unsigned short w_lds[256 * 72];    // weight slab [256 n][64 k +8]
  __shared__ int src_lds[64];
  __shared__ int dst_lds[64];

  int tid = threadIdx.x;
  int e0 = blockIdx.x * 64;
  if (tid < 64) {
    int d = EI[e0 + tid];
    dst_lds[tid] = min(max(d, 0), N_NODES - 1);
  } else if (tid < 128) {
    int s = EI[E_EDGES + e0 + (tid - 64)];
    src_lds[tid - 64] = min(max(s, 0), N_NODES - 1);
  }
  // stage 64x256 fp32 tile as bf16: 4096 float4 loads -> 16 iters of 256
  for (int it = 0; it < 16; ++it) {
    int i = it * 256 + tid;
    int r = i >> 6, c = i & 63;
    float4 v = *(const float4*)(edge_attr + (size_t)(e0 + r) * 256 + c * 4);
    unsigned short* d = ea_lds + r * 264 + c * 4;
    d[0] = f2bf(v.x); d[1] = f2bf(v.y); d[2] = f2bf(v.z); d[3] = f2bf(v.w);
  }
  __syncthreads();

  int w = tid >> 6, l = tid & 63, quad = l >> 4, lid = l & 15;
  int wc = w * 64;   // wave's column block (h-cols in G1b, n2 in G2)

  f32x4 macc[4][4];
#pragma unroll
  for (int a = 0; a < 4; ++a)
#pragma unroll
    for (int b = 0; b < 4; ++b) macc[a][b] = (f32x4){0.f, 0.f, 0.f, 0.f};

  for (int nc = 0; nc < 2; ++nc) {
    int n0 = nc * 256;
    __syncthreads();  // prior readers of uh_lds/w_lds done
    // stage U chunk (coalesced row gathers): 2048 uint4 = 64 rows x 256 cols
    for (int it = 0; it < 8; ++it) {
      int i = it * 256 + tid;
      int r = i >> 5, c = i & 31;
      uint4 v = *(const uint4*)(U + (size_t)src_lds[r] * 512 + n0 + c * 8);
      *(uint4*)(uh_lds + r * 264 + c * 8) = v;
    }
    // prefetch G1b slab 0
    uint4 R[8];
    for (int it = 0; it < 8; ++it) {
      int i = it * 256 + tid;
      int r = i >> 3, c = i & 7;
      R[it] = *(const uint4*)(W1bt + (size_t)(n0 + r) * 256 + c * 8);
    }
    f32x4 acc1[4][4];
#pragma unroll
    for (int a = 0; a < 4; ++a)
#pragma unroll
      for (int b = 0; b < 4; ++b) acc1[a][b] = (f32x4){0.f, 0.f, 0.f, 0.f};

    // ---- GEMM1b: h[:, n0:n0+256] partial = edge_attr @ W1b ----
    for (int s = 0; s < 4; ++s) {
      __syncthreads();            // readers of w_lds done / staging visible gate 1
      for (int it = 0; it < 8; ++it) {
        int i = it * 256 + tid;
        int r = i >> 3, c = i & 7;
        *(uint4*)(w_lds + r * 72 + c * 8) = R[it];
      }
      if (s < 3) {
        for (int it = 0; it < 8; ++it) {
          int i = it * 256 + tid;
          int r = i >> 3, c = i & 7;
          R[it] = *(const uint4*)(W1bt + (size_t)(n0 + r) * 256 + (s + 1) * 64 + c * 8);
        }
      }
      __syncthreads();            // slab visible
#pragma unroll
      for (int k2 = 0; k2 < 2; ++k2) {
        int ka = s * 64 + k2 * 32;
        bf16x8 af[4];
#pragma unroll
        for (int mf = 0; mf < 4; ++mf)
          af[mf] = *(const bf16x8*)(ea_lds + (mf * 16 + lid) * 264 + ka + quad * 8);
#pragma unroll
        for (int nf = 0; nf < 4; ++nf) {
          bf16x8 bfr = *(const bf16x8*)(w_lds + (wc + nf * 16 + lid) * 72 + k2 * 32 + quad * 8);
#pragma unroll
          for (int mf = 0; mf < 4; ++mf)
            acc1[mf][nf] = __builtin_amdgcn_mfma_f32_16x16x32_bf16(af[mf], bfr, acc1[mf][nf], 0, 0, 0);
        }
      }
    }
    // ---- epilogue1: h = relu(acc1 + U), pack bf16 ----
    unsigned hpack[4][4][2];
#pragma unroll
    for (int mf = 0; mf < 4; ++mf)
#pragma unroll
      for (int nf = 0; nf < 4; ++nf) {
        int colx = wc + nf * 16 + lid;
#pragma unroll
        for (int rp = 0; rp < 2; ++rp) {
          int rowb = mf * 16 + quad * 4 + rp * 2;
          float h0 = acc1[mf][nf][rp * 2 + 0] + bf2f(uh_lds[rowb * 264 + colx]);
          float h1 = acc1[mf][nf][rp * 2 + 1] + bf2f(uh_lds[(rowb + 1) * 264 + colx]);
          h0 = h0 > 0.f ? h0 : 0.f;
          h1 = h1 > 0.f ? h1 : 0.f;
          hpack[mf][nf][rp] = (unsigned)f2bf(h0) | ((unsigned)f2bf(h1) << 16);
        }
      }
    // prefetch G2 slab 0
    for (int it = 0; it < 8; ++it) {
      int i = it * 256 + tid;
      int r = i >> 3, c = i & 7;
      R[it] = *(const uint4*)(W2t + (size_t)r * 512 + n0 + c * 8);
    }
    __syncthreads();   // all waves done reading U chunk + G1b slab
    // write h into uh_lds
#pragma unroll
    for (int mf = 0; mf < 4; ++mf)
#pragma unroll
      for (int nf = 0; nf < 4; ++nf) {
        int colx = wc + nf * 16 + lid;
#pragma unroll
        for (int rp = 0; rp < 2; ++rp) {
          int rowb = mf * 16 + quad * 4 + rp * 2;
          unsigned p = hpack[mf][nf][rp];
          uh_lds[rowb * 264 + colx] = (unsigned short)(p & 0xFFFFu);
          uh_lds[(rowb + 1) * 264 + colx] = (unsigned short)(p >> 16);
        }
      }
    // ---- GEMM2: messages += h_chunk @ W2[n0:n0+256, :] ----
    for (int s = 0; s < 4; ++s) {
      for (int it = 0; it < 8; ++it) {
        int i = it * 256 + tid;
        int r = i >> 3, c = i & 7;
        *(uint4*)(w_lds + r * 72 + c * 8) = R[it];
      }
      if (s < 3) {
        for (int it = 0; it < 8; ++it) {
          int i = it * 256 + tid;
          int r = i >> 3, c = i & 7;
          R[it] = *(const uint4*)(W2t + (size_t)r * 512 + n0 + (s + 1) * 64 + c * 8);
        }
      }
      __syncthreads();           // h + slab visible
#pragma unroll
      for (int k2 = 0; k2 < 2; ++k2) {
        int kc = s * 64 + k2 * 32;
        bf16x8 af[4];
#pragma unroll
        for (int mf = 0; mf < 4; ++mf)
          af[mf] = *(const bf16x8*)(uh_lds + (mf * 16 + lid) * 264 + kc + quad * 8);
#pragma unroll
        for (int nf = 0; nf < 4; ++nf) {
          bf16x8 bfr = *(const bf16x8*)(w_lds + (wc + nf * 16 + lid) * 72 + k2 * 32 + quad * 8);
#pragma unroll
          for (int mf = 0; mf < 4; ++mf)
            macc[mf][nf] = __builtin_amdgcn_mfma_f32_16x16x32_bf16(af[mf], bfr, macc[mf][nf], 0, 0, 0);
        }
      }
      if (s < 3) __syncthreads();  // before overwriting w_lds
    }
  }
  // ---- epilogue2: + b2, atomic scatter to out[dst] ----
#pragma unroll
  for (int nf = 0; nf < 4; ++nf) {
    int col = wc + nf * 16 + lid;
    float b2v = b2[col];
#pragma unroll
    for (int mf = 0; mf < 4; ++mf)
#pragma unroll
      for (int reg = 0; reg < 4; ++reg) {
        int node = dst_lds[mf * 16 + quad * 4 + reg];
        atomicAdd(out + (size_t)node * 256 + col, macc[mf][nf][reg] + b2v);
      }
  }
}

extern "C" void kernel_launch(void* const* d_in, const int* in_sizes, int n_in,
                              void* d_out, int out_size, void* d_ws, size_t ws_size,
                              hipStream_t stream) {
  const float* x_in      = (const float*)d_in[1];
  const int* EI          = (const int*)d_in[2];
  const float* edge_attr = (const float*)d_in[3];
  const float* W1        = (const float*)d_in[4];
  const float* b1        = (const float*)d_in[5];
  const float* W2        = (const float*)d_in[6];
  const float* b2        = (const float*)d_in[7];
  float* out = (float*)d_out;

  // ws layout: weights first (small), then U.
  // W1at | W1bt | W2t : 3 * 512*256*2 B = 786,432 B ; U = 10000*512*2 = 10,240,000 B
  unsigned short* W1at = (unsigned short*)d_ws;
  unsigned short* W1bt = W1at + 512 * 256;
  unsigned short* W2t  = W1bt + 512 * 256;
  unsigned short* U    = W2t + 256 * 512;

  hipMemsetAsync(d_out, 0, (size_t)out_size * sizeof(float), stream);
  prep_kernel<<<1024, 256, 0, stream>>>(W1, W2, W1at, W1bt, W2t);
  u_kernel<<<157, 256, 0, stream>>>(x_in, W1at, b1, U);
  main_kernel<<<5000, 256, 0, stream>>>(EI, edge_attr, W1bt, W2t, U, b2, out);
}

// Round 3
// 980.339 us; speedup vs baseline: 1.6208x; 1.6208x over previous
//
#include <hip/hip_runtime.h>

#define E_EDGES 320000
#define N_NODES 10000

typedef __attribute__((ext_vector_type(8))) short bf16x8;
typedef __attribute__((ext_vector_type(4))) float f32x4;

__device__ __forceinline__ unsigned short f2bf(float x) {
  union { float f; unsigned u; } v; v.f = x;
  unsigned r = v.u + 0x7FFFu + ((v.u >> 16) & 1u);
  return (unsigned short)(r >> 16);
}
__device__ __forceinline__ float bf2f(unsigned short s) {
  union { unsigned u; float f; } v; v.u = ((unsigned)s) << 16;
  return v.f;
}

// ---------------- prep: W1 -> W1at/W1bt bf16 [n][k], W2 -> W2t bf16 [n][k] ----
__global__ __launch_bounds__(256) void prep_kernel(
    const float* __restrict__ W1, const float* __restrict__ W2,
    unsigned short* __restrict__ W1at, unsigned short* __restrict__ W1bt,
    unsigned short* __restrict__ W2t) {
  int tid = blockIdx.x * 256 + threadIdx.x;
  if (tid < 512 * 256) {
    int n = tid >> 8, k = tid & 255;          // W1at/W1bt: [512 n][256 k]
    W1at[tid] = f2bf(W1[k * 512 + n]);
    W1bt[tid] = f2bf(W1[(k + 256) * 512 + n]);
  } else {
    int t = tid - 512 * 256;
    if (t < 256 * 512) {
      int n = t >> 9, k = t & 511;            // W2t: [256 n][512 k]
      W2t[t] = f2bf(W2[k * 256 + n]);
    }
  }
}

// ---------------- U = x_in @ W1[0:256,:] + b1   -> bf16 [node][512] ----------
__global__ __launch_bounds__(256) void u_kernel(
    const float* __restrict__ x_in, const unsigned short* __restrict__ W1at,
    const float* __restrict__ b1, unsigned short* __restrict__ U) {
  __shared__ unsigned short x_lds[64 * 264];
  int tid = threadIdx.x;
  int m0g = blockIdx.x * 64;
  for (int it = 0; it < 16; ++it) {
    int i = it * 256 + tid;
    int r = i >> 6, c = i & 63;
    int node = m0g + r;
    float4 v = make_float4(0.f, 0.f, 0.f, 0.f);
    if (node < N_NODES) v = *(const float4*)(x_in + node * 256 + c * 4);
    ushort4 s4;
    s4.x = f2bf(v.x); s4.y = f2bf(v.y); s4.z = f2bf(v.z); s4.w = f2bf(v.w);
    *(ushort4*)(x_lds + r * 264 + c * 4) = s4;
  }
  __syncthreads();
  int w = tid >> 6, l = tid & 63, quad = l >> 4, lid = l & 15;
  int cb = w * 128;
  f32x4 acc[4][8];
#pragma unroll
  for (int a = 0; a < 4; ++a)
#pragma unroll
    for (int b = 0; b < 8; ++b) acc[a][b] = (f32x4){0.f, 0.f, 0.f, 0.f};
#pragma unroll
  for (int kk = 0; kk < 8; ++kk) {
    bf16x8 af[4];
#pragma unroll
    for (int mf = 0; mf < 4; ++mf)
      af[mf] = *(const bf16x8*)(x_lds + (mf * 16 + lid) * 264 + kk * 32 + quad * 8);
#pragma unroll
    for (int nf = 0; nf < 8; ++nf) {
      bf16x8 bfr = *(const bf16x8*)(W1at + (cb + nf * 16 + lid) * 256 + kk * 32 + quad * 8);
#pragma unroll
      for (int mf = 0; mf < 4; ++mf)
        acc[mf][nf] = __builtin_amdgcn_mfma_f32_16x16x32_bf16(af[mf], bfr, acc[mf][nf], 0, 0, 0);
    }
  }
#pragma unroll
  for (int nf = 0; nf < 8; ++nf) {
    int col = cb + nf * 16 + lid;
    float b1v = b1[col];
#pragma unroll
    for (int mf = 0; mf < 4; ++mf)
#pragma unroll
      for (int reg = 0; reg < 4; ++reg) {
        int node = m0g + mf * 16 + quad * 4 + reg;
        if (node < N_NODES) U[node * 512 + col] = f2bf(acc[mf][nf][reg] + b1v);
      }
  }
}

// ---------------- fused edge MLP + scatter, v2 ------------------------------
// 64 edges/WG, 4 waves. Hidden split into 4 chunks of 128 (h tile 64x136).
// Weights + U read straight from global (L2-resident); LDS = ea + h + idx only
// (51.7 KB -> 3 WGs/CU). 9 barriers/WG vs 28 in v1.
#define EA_OFF 0            // 64 x 264 shorts = 33792 B
#define H_OFF  (64 * 264)   // 64 x 136 shorts = 17408 B
#define IDX_OFF (H_OFF + 64 * 136)  // 128 ints (shorts x256) = 512 B
__global__ __launch_bounds__(256, 3) void main_kernel(
    const int* __restrict__ EI, const float* __restrict__ edge_attr,
    const unsigned short* __restrict__ W1bt, const unsigned short* __restrict__ W2t,
    const unsigned short* __restrict__ U, const float* __restrict__ b2,
    float* __restrict__ out) {
  __shared__ unsigned short lds[64 * 264 + 64 * 136 + 256];
  int* idx_lds = (int*)(lds + IDX_OFF);   // [0..63]=dst, [64..127]=src

  int tid = threadIdx.x;
  int e0 = blockIdx.x * 64;
  if (tid < 64) {
    int d = EI[e0 + tid];
    idx_lds[tid] = min(max(d, 0), N_NODES - 1);
  } else if (tid < 128) {
    int s = EI[E_EDGES + e0 + (tid - 64)];
    idx_lds[tid] = min(max(s, 0), N_NODES - 1);
  }
  // stage edge_attr tile 64x256 fp32 -> bf16 LDS (stride 264)
  for (int it = 0; it < 16; ++it) {
    int i = it * 256 + tid;
    int r = i >> 6, c = i & 63;
    float4 v = *(const float4*)(edge_attr + (size_t)(e0 + r) * 256 + c * 4);
    ushort4 s4;
    s4.x = f2bf(v.x); s4.y = f2bf(v.y); s4.z = f2bf(v.z); s4.w = f2bf(v.w);
    *(ushort4*)(lds + EA_OFF + r * 264 + c * 4) = s4;
  }
  __syncthreads();

  int w = tid >> 6, l = tid & 63, quad = l >> 4, lid = l & 15;

  f32x4 macc[4][4];   // GEMM2 accum: 64 out cols/wave, 64 edges
#pragma unroll
  for (int a = 0; a < 4; ++a)
#pragma unroll
    for (int b = 0; b < 4; ++b) macc[a][b] = (f32x4){0.f, 0.f, 0.f, 0.f};

  for (int nc = 0; nc < 4; ++nc) {
    int n0 = nc * 128;                 // hidden chunk base
    // ---- GEMM1b: acc1 = ea @ W1b[:, n0:n0+128], wave covers 32 cols ----
    f32x4 acc1[4][2];
#pragma unroll
    for (int a = 0; a < 4; ++a)
#pragma unroll
      for (int b = 0; b < 2; ++b) acc1[a][b] = (f32x4){0.f, 0.f, 0.f, 0.f};
#pragma unroll
    for (int s = 0; s < 8; ++s) {      // k = s*32
      int ka = s * 32 + quad * 8;
      bf16x8 af[4];
#pragma unroll
      for (int mf = 0; mf < 4; ++mf)
        af[mf] = *(const bf16x8*)(lds + EA_OFF + (mf * 16 + lid) * 264 + ka);
#pragma unroll
      for (int nf = 0; nf < 2; ++nf) {
        int hrow = n0 + w * 32 + nf * 16 + lid;           // hidden col
        bf16x8 bfr = *(const bf16x8*)(W1bt + (size_t)hrow * 256 + ka);
#pragma unroll
        for (int mf = 0; mf < 4; ++mf)
          acc1[mf][nf] = __builtin_amdgcn_mfma_f32_16x16x32_bf16(af[mf], bfr, acc1[mf][nf], 0, 0, 0);
      }
    }
    // ---- epilogue1: h = relu(acc1 + U[src]), U direct from global ----
    unsigned hpack[4][2][2];
#pragma unroll
    for (int nf = 0; nf < 2; ++nf) {
      int colg = n0 + w * 32 + nf * 16 + lid;             // global hidden col
#pragma unroll
      for (int mf = 0; mf < 4; ++mf) {
#pragma unroll
        for (int rp = 0; rp < 2; ++rp) {
          int row0 = mf * 16 + quad * 4 + rp * 2;
          int s0 = idx_lds[64 + row0];
          int s1 = idx_lds[64 + row0 + 1];
          float h0 = acc1[mf][nf][rp * 2 + 0] + bf2f(U[(size_t)s0 * 512 + colg]);
          float h1 = acc1[mf][nf][rp * 2 + 1] + bf2f(U[(size_t)s1 * 512 + colg]);
          h0 = h0 > 0.f ? h0 : 0.f;
          h1 = h1 > 0.f ? h1 : 0.f;
          hpack[mf][nf][rp] = (unsigned)f2bf(h0) | ((unsigned)f2bf(h1) << 16);
        }
      }
    }
    __syncthreads();   // prev chunk's GEMM2 readers of h done
#pragma unroll
    for (int mf = 0; mf < 4; ++mf)
#pragma unroll
      for (int nf = 0; nf < 2; ++nf) {
        int colx = w * 32 + nf * 16 + lid;                // col within chunk
#pragma unroll
        for (int rp = 0; rp < 2; ++rp) {
          int row0 = mf * 16 + quad * 4 + rp * 2;
          unsigned p = hpack[mf][nf][rp];
          lds[H_OFF + row0 * 136 + colx] = (unsigned short)(p & 0xFFFFu);
          lds[H_OFF + (row0 + 1) * 136 + colx] = (unsigned short)(p >> 16);
        }
      }
    __syncthreads();   // h visible
    // ---- GEMM2: macc += h_chunk @ W2[n0:n0+128, :], wave covers 64 out cols ----
#pragma unroll
    for (int s2 = 0; s2 < 4; ++s2) {   // k local = s2*32
      int kl = s2 * 32 + quad * 8;
      bf16x8 af[4];
#pragma unroll
      for (int mf = 0; mf < 4; ++mf)
        af[mf] = *(const bf16x8*)(lds + H_OFF + (mf * 16 + lid) * 136 + kl);
#pragma unroll
      for (int nf = 0; nf < 4; ++nf) {
        int orow = w * 64 + nf * 16 + lid;                // out col
        bf16x8 bfr = *(const bf16x8*)(W2t + (size_t)orow * 512 + n0 + kl);
#pragma unroll
        for (int mf = 0; mf < 4; ++mf)
          macc[mf][nf] = __builtin_amdgcn_mfma_f32_16x16x32_bf16(af[mf], bfr, macc[mf][nf], 0, 0, 0);
      }
    }
  }
  // ---- epilogue2: + b2, atomic scatter to out[dst] ----
#pragma unroll
  for (int nf = 0; nf < 4; ++nf) {
    int col = w * 64 + nf * 16 + lid;
    float b2v = b2[col];
#pragma unroll
    for (int mf = 0; mf < 4; ++mf)
#pragma unroll
      for (int reg = 0; reg < 4; ++reg) {
        int node = idx_lds[mf * 16 + quad * 4 + reg];
        atomicAdd(out + (size_t)node * 256 + col, macc[mf][nf][reg] + b2v);
      }
  }
}

extern "C" void kernel_launch(void* const* d_in, const int* in_sizes, int n_in,
                              void* d_out, int out_size, void* d_ws, size_t ws_size,
                              hipStream_t stream) {
  const float* x_in      = (const float*)d_in[1];
  const int* EI          = (const int*)d_in[2];
  const float* edge_attr = (const float*)d_in[3];
  const float* W1        = (const float*)d_in[4];
  const float* b1        = (const float*)d_in[5];
  const float* W2        = (const float*)d_in[6];
  const float* b2        = (const float*)d_in[7];
  float* out = (float*)d_out;

  // ws: W1at | W1bt | W2t (786,432 B) then U (10,240,000 B)
  unsigned short* W1at = (unsigned short*)d_ws;
  unsigned short* W1bt = W1at + 512 * 256;
  unsigned short* W2t  = W1bt + 512 * 256;
  unsigned short* U    = W2t + 256 * 512;

  hipMemsetAsync(d_out, 0, (size_t)out_size * sizeof(float), stream);
  prep_kernel<<<1024, 256, 0, stream>>>(W1, W2, W1at, W1bt, W2t);
  u_kernel<<<157, 256, 0, stream>>>(x_in, W1at, b1, U);
  main_kernel<<<5000, 256, 0, stream>>>(EI, edge_attr, W1bt, W2t, U, b2, out);
}

// Round 4
// 924.112 us; speedup vs baseline: 1.7194x; 1.0608x over previous
//
#include <hip/hip_runtime.h>

#define E_EDGES 320000
#define N_NODES 10000

typedef __attribute__((ext_vector_type(8))) short bf16x8;
typedef __attribute__((ext_vector_type(4))) float f32x4;

__device__ __forceinline__ unsigned short f2bf(float x) {
  union { float f; unsigned u; } v; v.f = x;
  unsigned r = v.u + 0x7FFFu + ((v.u >> 16) & 1u);
  return (unsigned short)(r >> 16);
}
__device__ __forceinline__ float bf2f(unsigned short s) {
  union { unsigned u; float f; } v; v.u = ((unsigned)s) << 16;
  return v.f;
}

// ---------------- prep: W1 -> W1at/W1bt bf16 [n][k], W2 -> W2t bf16 [n][k] ----
__global__ __launch_bounds__(256) void prep_kernel(
    const float* __restrict__ W1, const float* __restrict__ W2,
    unsigned short* __restrict__ W1at, unsigned short* __restrict__ W1bt,
    unsigned short* __restrict__ W2t) {
  int tid = blockIdx.x * 256 + threadIdx.x;
  if (tid < 512 * 256) {
    int n = tid >> 8, k = tid & 255;          // W1at/W1bt: [512 n][256 k]
    W1at[tid] = f2bf(W1[k * 512 + n]);
    W1bt[tid] = f2bf(W1[(k + 256) * 512 + n]);
  } else {
    int t = tid - 512 * 256;
    if (t < 256 * 512) {
      int n = t >> 9, k = t & 511;            // W2t: [256 n][512 k]
      W2t[t] = f2bf(W2[k * 256 + n]);
    }
  }
}

// ---------------- U = x_in @ W1[0:256,:] + b1   -> bf16 [node][512] ----------
// grid (157, 4): WG covers 64 nodes x 128 cols; B-frags pipelined.
__global__ __launch_bounds__(256) void u_kernel(
    const float* __restrict__ x_in, const unsigned short* __restrict__ W1at,
    const float* __restrict__ b1, unsigned short* __restrict__ U) {
  __shared__ unsigned short x_lds[64 * 264];
  int tid = threadIdx.x;
  int m0g = blockIdx.x * 64;
  for (int it = 0; it < 16; ++it) {
    int i = it * 256 + tid;
    int r = i >> 6, c = i & 63;
    int node = m0g + r;
    float4 v = make_float4(0.f, 0.f, 0.f, 0.f);
    if (node < N_NODES) v = *(const float4*)(x_in + node * 256 + c * 4);
    ushort4 s4;
    s4.x = f2bf(v.x); s4.y = f2bf(v.y); s4.z = f2bf(v.z); s4.w = f2bf(v.w);
    *(ushort4*)(x_lds + r * 264 + c * 4) = s4;
  }
  __syncthreads();
  int w = tid >> 6, l = tid & 63, quad = l >> 4, lid = l & 15;
  int cb = blockIdx.y * 128 + w * 32;
  f32x4 acc[4][2];
#pragma unroll
  for (int a = 0; a < 4; ++a)
#pragma unroll
    for (int b = 0; b < 2; ++b) acc[a][b] = (f32x4){0.f, 0.f, 0.f, 0.f};
  bf16x8 bc[2], bn[2];
#pragma unroll
  for (int nf = 0; nf < 2; ++nf)
    bc[nf] = *(const bf16x8*)(W1at + (size_t)(cb + nf * 16 + lid) * 256 + quad * 8);
#pragma unroll
  for (int kk = 0; kk < 8; ++kk) {
    if (kk < 7) {
#pragma unroll
      for (int nf = 0; nf < 2; ++nf)
        bn[nf] = *(const bf16x8*)(W1at + (size_t)(cb + nf * 16 + lid) * 256 + (kk + 1) * 32 + quad * 8);
    }
    bf16x8 af[4];
#pragma unroll
    for (int mf = 0; mf < 4; ++mf)
      af[mf] = *(const bf16x8*)(x_lds + (mf * 16 + lid) * 264 + kk * 32 + quad * 8);
#pragma unroll
    for (int nf = 0; nf < 2; ++nf)
#pragma unroll
      for (int mf = 0; mf < 4; ++mf)
        acc[mf][nf] = __builtin_amdgcn_mfma_f32_16x16x32_bf16(af[mf], bc[nf], acc[mf][nf], 0, 0, 0);
#pragma unroll
    for (int nf = 0; nf < 2; ++nf) bc[nf] = bn[nf];
  }
#pragma unroll
  for (int nf = 0; nf < 2; ++nf) {
    int col = cb + nf * 16 + lid;
    float b1v = b1[col];
#pragma unroll
    for (int mf = 0; mf < 4; ++mf)
#pragma unroll
      for (int reg = 0; reg < 4; ++reg) {
        int node = m0g + mf * 16 + quad * 4 + reg;
        if (node < N_NODES) U[node * 512 + col] = f2bf(acc[mf][nf][reg] + b1v);
      }
  }
}

// ---------------- fused edge MLP + scatter, v3 (pipelined) -------------------
#define EA_OFF 0            // 64 x 264 shorts = 33792 B
#define H_OFF  (64 * 264)   // 64 x 136 shorts = 17408 B
#define IDX_OFF (H_OFF + 64 * 136)  // 128 ints = 512 B
__global__ __launch_bounds__(256, 3) void main_kernel(
    const int* __restrict__ EI, const float* __restrict__ edge_attr,
    const unsigned short* __restrict__ W1bt, const unsigned short* __restrict__ W2t,
    const unsigned short* __restrict__ U, const float* __restrict__ b2,
    float* __restrict__ out) {
  __shared__ unsigned short lds[64 * 264 + 64 * 136 + 256];
  int* idx_lds = (int*)(lds + IDX_OFF);   // [0..63]=dst, [64..127]=src

  int tid = threadIdx.x;
  int e0 = blockIdx.x * 64;
  if (tid < 64) {
    int d = EI[e0 + tid];
    idx_lds[tid] = min(max(d, 0), N_NODES - 1);
  } else if (tid < 128) {
    int s = EI[E_EDGES + e0 + (tid - 64)];
    idx_lds[tid] = min(max(s, 0), N_NODES - 1);
  }
  for (int it = 0; it < 16; ++it) {
    int i = it * 256 + tid;
    int r = i >> 6, c = i & 63;
    float4 v = *(const float4*)(edge_attr + (size_t)(e0 + r) * 256 + c * 4);
    ushort4 s4;
    s4.x = f2bf(v.x); s4.y = f2bf(v.y); s4.z = f2bf(v.z); s4.w = f2bf(v.w);
    *(ushort4*)(lds + EA_OFF + r * 264 + c * 4) = s4;
  }
  __syncthreads();

  int w = tid >> 6, l = tid & 63, quad = l >> 4, lid = l & 15;

  f32x4 macc[4][4];
#pragma unroll
  for (int a = 0; a < 4; ++a)
#pragma unroll
    for (int b = 0; b < 4; ++b) macc[a][b] = (f32x4){0.f, 0.f, 0.f, 0.f};

  for (int nc = 0; nc < 4; ++nc) {
    int n0 = nc * 128;
    // ---- U prefetch: 32 scalar loads issued up front, packed to 16 u32 ----
    unsigned ur[4][2][2];   // [mf][nf][rp] = rows (rp*2 | rp*2+1 <<16)
#pragma unroll
    for (int mf = 0; mf < 4; ++mf)
#pragma unroll
      for (int rp = 0; rp < 2; ++rp) {
        int r0 = mf * 16 + quad * 4 + rp * 2;
        const unsigned short* p0 = U + (size_t)idx_lds[64 + r0] * 512 + n0 + w * 32 + lid;
        const unsigned short* p1 = U + (size_t)idx_lds[64 + r0 + 1] * 512 + n0 + w * 32 + lid;
#pragma unroll
        for (int nf = 0; nf < 2; ++nf)
          ur[mf][nf][rp] = (unsigned)p0[nf * 16] | ((unsigned)p1[nf * 16] << 16);
      }
    // ---- GEMM1b: acc1 = ea @ W1b[:, n0:n0+128], B-frags double-buffered ----
    f32x4 acc1[4][2];
#pragma unroll
    for (int a = 0; a < 4; ++a)
#pragma unroll
      for (int b = 0; b < 2; ++b) acc1[a][b] = (f32x4){0.f, 0.f, 0.f, 0.f};
    int hrow = n0 + w * 32 + lid;
    bf16x8 b1c[2], b1n[2];
#pragma unroll
    for (int nf = 0; nf < 2; ++nf)
      b1c[nf] = *(const bf16x8*)(W1bt + (size_t)(hrow + nf * 16) * 256 + quad * 8);
#pragma unroll
    for (int s = 0; s < 8; ++s) {
      if (s < 7) {
#pragma unroll
        for (int nf = 0; nf < 2; ++nf)
          b1n[nf] = *(const bf16x8*)(W1bt + (size_t)(hrow + nf * 16) * 256 + (s + 1) * 32 + quad * 8);
      }
      int ka = s * 32 + quad * 8;
      bf16x8 af[4];
#pragma unroll
      for (int mf = 0; mf < 4; ++mf)
        af[mf] = *(const bf16x8*)(lds + EA_OFF + (mf * 16 + lid) * 264 + ka);
#pragma unroll
      for (int nf = 0; nf < 2; ++nf)
#pragma unroll
        for (int mf = 0; mf < 4; ++mf)
          acc1[mf][nf] = __builtin_amdgcn_mfma_f32_16x16x32_bf16(af[mf], b1c[nf], acc1[mf][nf], 0, 0, 0);
#pragma unroll
      for (int nf = 0; nf < 2; ++nf) b1c[nf] = b1n[nf];
    }
    // ---- epilogue1: h = relu(acc1 + U[src]) using prefetched ur ----
    unsigned hpack[4][2][2];
#pragma unroll
    for (int nf = 0; nf < 2; ++nf)
#pragma unroll
      for (int mf = 0; mf < 4; ++mf)
#pragma unroll
        for (int rp = 0; rp < 2; ++rp) {
          unsigned p = ur[mf][nf][rp];
          float h0 = acc1[mf][nf][rp * 2 + 0] + bf2f((unsigned short)(p & 0xFFFFu));
          float h1 = acc1[mf][nf][rp * 2 + 1] + bf2f((unsigned short)(p >> 16));
          h0 = h0 > 0.f ? h0 : 0.f;
          h1 = h1 > 0.f ? h1 : 0.f;
          hpack[mf][nf][rp] = (unsigned)f2bf(h0) | ((unsigned)f2bf(h1) << 16);
        }
    __syncthreads();   // prev chunk's GEMM2 readers of h done
#pragma unroll
    for (int mf = 0; mf < 4; ++mf)
#pragma unroll
      for (int nf = 0; nf < 2; ++nf) {
        int colx = w * 32 + nf * 16 + lid;
#pragma unroll
        for (int rp = 0; rp < 2; ++rp) {
          int row0 = mf * 16 + quad * 4 + rp * 2;
          unsigned p = hpack[mf][nf][rp];
          lds[H_OFF + row0 * 136 + colx] = (unsigned short)(p & 0xFFFFu);
          lds[H_OFF + (row0 + 1) * 136 + colx] = (unsigned short)(p >> 16);
        }
      }
    __syncthreads();   // h visible
    // ---- GEMM2: macc += h @ W2[n0:n0+128, :], B-frags double-buffered ----
    int orow = w * 64 + lid;
    bf16x8 c2[4], n2[4];
#pragma unroll
    for (int nf = 0; nf < 4; ++nf)
      c2[nf] = *(const bf16x8*)(W2t + (size_t)(orow + nf * 16) * 512 + n0 + quad * 8);
#pragma unroll
    for (int s2 = 0; s2 < 4; ++s2) {
      if (s2 < 3) {
#pragma unroll
        for (int nf = 0; nf < 4; ++nf)
          n2[nf] = *(const bf16x8*)(W2t + (size_t)(orow + nf * 16) * 512 + n0 + (s2 + 1) * 32 + quad * 8);
      }
      int kl = s2 * 32 + quad * 8;
      bf16x8 af[4];
#pragma unroll
      for (int mf = 0; mf < 4; ++mf)
        af[mf] = *(const bf16x8*)(lds + H_OFF + (mf * 16 + lid) * 136 + kl);
#pragma unroll
      for (int nf = 0; nf < 4; ++nf)
#pragma unroll
        for (int mf = 0; mf < 4; ++mf)
          macc[mf][nf] = __builtin_amdgcn_mfma_f32_16x16x32_bf16(af[mf], c2[nf], macc[mf][nf], 0, 0, 0);
#pragma unroll
      for (int nf = 0; nf < 4; ++nf) c2[nf] = n2[nf];
    }
  }
  // ---- epilogue2: + b2, atomic scatter to out[dst] ----
#pragma unroll
  for (int nf = 0; nf < 4; ++nf) {
    int col = w * 64 + nf * 16 + lid;
    float b2v = b2[col];
#pragma unroll
    for (int mf = 0; mf < 4; ++mf)
#pragma unroll
      for (int reg = 0; reg < 4; ++reg) {
        int node = idx_lds[mf * 16 + quad * 4 + reg];
        atomicAdd(out + (size_t)node * 256 + col, macc[mf][nf][reg] + b2v);
      }
  }
}

extern "C" void kernel_launch(void* const* d_in, const int* in_sizes, int n_in,
                              void* d_out, int out_size, void* d_ws, size_t ws_size,
                              hipStream_t stream) {
  const float* x_in      = (const float*)d_in[1];
  const int* EI          = (const int*)d_in[2];
  const float* edge_attr = (const float*)d_in[3];
  const float* W1        = (const float*)d_in[4];
  const float* b1        = (const float*)d_in[5];
  const float* W2        = (const float*)d_in[6];
  const float* b2        = (const float*)d_in[7];
  float* out = (float*)d_out;

  unsigned short* W1at = (unsigned short*)d_ws;
  unsigned short* W1bt = W1at + 512 * 256;
  unsigned short* W2t  = W1bt + 512 * 256;
  unsigned short* U    = W2t + 256 * 512;

  hipMemsetAsync(d_out, 0, (size_t)out_size * sizeof(float), stream);
  prep_kernel<<<1024, 256, 0, stream>>>(W1, W2, W1at, W1bt, W2t);
  u_kernel<<<dim3(157, 4), 256, 0, stream>>>(x_in, W1at, b1, U);
  main_kernel<<<5000, 256, 0, stream>>>(EI, edge_attr, W1bt, W2t, U, b2, out);
}